// Round 1
// baseline (882.169 us; speedup 1.0000x reference)
//
#include <hip/hip_runtime.h>
#include <hip/hip_bf16.h>

using bf16 = __hip_bfloat16;
using short8 = __attribute__((ext_vector_type(8))) short;
using f32x4  = __attribute__((ext_vector_type(4))) float;

#define GLDS16(g, l) __builtin_amdgcn_global_load_lds( \
    (const __attribute__((address_space(1))) void*)(g), \
    (__attribute__((address_space(3))) void*)(l), 16, 0, 0)

constexpr int S  = 2048;
constexpr int D  = 1280;
constexpr int H  = 16;
constexpr int HD = 80;
constexpr int IM = 5120;

// ---------------- weight transpose: fp32 [K][N] -> bf16 [N][K] ----------------
__global__ __launch_bounds__(256) void transpose_w(const float* __restrict__ W,
                                                   bf16* __restrict__ Wt,
                                                   int K, int N) {
  __shared__ float t[32][33];
  int tx = threadIdx.x & 31, ty = threadIdx.x >> 5;
  int n0 = blockIdx.x * 32, k0 = blockIdx.y * 32;
#pragma unroll
  for (int i = 0; i < 4; i++)
    t[ty + i * 8][tx] = W[(size_t)(k0 + ty + i * 8) * N + n0 + tx];
  __syncthreads();
#pragma unroll
  for (int i = 0; i < 4; i++)
    Wt[(size_t)(n0 + ty + i * 8) * K + k0 + tx] = __float2bfloat16(t[tx][ty + i * 8]);
}

// ---------------- V transpose: bf16 [H][S][HD] -> [H][HD][S] ----------------
__global__ __launch_bounds__(256) void transpose_v(const bf16* __restrict__ v,
                                                   bf16* __restrict__ vt) {
  __shared__ bf16 t[16][17];
  int tx = threadIdx.x & 15, ty = threadIdx.x >> 4;
  int s0 = blockIdx.x * 16, d0 = blockIdx.y * 16, h = blockIdx.z;
  t[ty][tx] = v[(size_t)(h * S + s0 + ty) * HD + d0 + tx];
  __syncthreads();
  vt[(size_t)(h * HD + d0 + ty) * S + s0 + tx] = t[tx][ty];
}

// ---------------- layernorm: fp32 x [S][D] -> bf16 h ----------------
__global__ __launch_bounds__(256) void layernorm_k(const float* __restrict__ x,
                                                   const float* __restrict__ g,
                                                   const float* __restrict__ b,
                                                   bf16* __restrict__ h) {
  int row = blockIdx.x, tid = threadIdx.x;
  const float* xr = x + (size_t)row * D;
  float v[5], s1 = 0.f, s2 = 0.f;
#pragma unroll
  for (int i = 0; i < 5; i++) {
    v[i] = xr[tid + i * 256];
    s1 += v[i]; s2 += v[i] * v[i];
  }
#pragma unroll
  for (int o = 32; o > 0; o >>= 1) {
    s1 += __shfl_down(s1, o);
    s2 += __shfl_down(s2, o);
  }
  __shared__ float r1[4], r2[4];
  if ((tid & 63) == 0) { r1[tid >> 6] = s1; r2[tid >> 6] = s2; }
  __syncthreads();
  s1 = r1[0] + r1[1] + r1[2] + r1[3];
  s2 = r2[0] + r2[1] + r2[2] + r2[3];
  float mean = s1 * (1.f / D);
  float rstd = rsqrtf(s2 * (1.f / D) - mean * mean + 1e-6f);
  bf16* hr = h + (size_t)row * D;
#pragma unroll
  for (int i = 0; i < 5; i++) {
    int c = tid + i * 256;
    hr[c] = __float2bfloat16((v[i] - mean) * rstd * g[c] + b[c]);
  }
}

// ---------------- RoPE (in-place on q,k [H][S][HD]) ----------------
__global__ __launch_bounds__(256) void rope_k(bf16* __restrict__ q, bf16* __restrict__ k,
                                              const float* __restrict__ cs,
                                              const float* __restrict__ sn) {
  int idx = blockIdx.x * 256 + threadIdx.x;   // 2*H*S*40 threads
  int p  = idx % 40;
  int t  = idx / 40;
  int s  = t & (S - 1);
  int t2 = t >> 11;
  int hh = t2 & (H - 1);
  bf16* base = ((t2 >> 4) ? k : q) + (size_t)(hh * S + s) * HD;
  float c0 = cs[s * HD + p],      s0 = sn[s * HD + p];
  float c1 = cs[s * HD + p + 40], s1 = sn[s * HD + p + 40];
  float x0 = __bfloat162float(base[p]);
  float x1 = __bfloat162float(base[p + 40]);
  base[p]      = __float2bfloat16(x0 * c0 - x1 * s0);
  base[p + 40] = __float2bfloat16(x1 * c1 + x0 * s1);
}

// ---------------- GEMM: A[2048][K] x Bt[N][K] (+bias) with epilogues ----------------
// EPI 0: split into q/k/v buffers [3][H][S][HD] bf16
// EPI 1: residual add into fp32 X[2048][N]
// EPI 2: exact GELU -> bf16 O[2048][N]
template <int EPI, int N, int K>
__global__ __launch_bounds__(256, 2) void gemm_bt(const bf16* __restrict__ A,
                                                  const bf16* __restrict__ Bt,
                                                  const float* __restrict__ bias,
                                                  float* __restrict__ X,
                                                  bf16* __restrict__ O) {
  __shared__ __align__(16) short As[128 * 32];
  __shared__ __align__(16) short Bs[128 * 32];
  int tid = threadIdx.x, lane = tid & 63, wid = tid >> 6;
  int l15 = lane & 15, l4 = lane >> 4;
  int wr = wid >> 1, wc = wid & 1;
  int rowBase = blockIdx.y * 128, colBase = blockIdx.x * 128;
  const bf16* Ab = A  + (size_t)rowBase * K;
  const bf16* Bb = Bt + (size_t)colBase * K;

  f32x4 acc[4][4] = {};

  for (int kt = 0; kt < K / 32; kt++) {
#pragma unroll
    for (int i = 0; i < 2; i++) {
      int cb = wid * 128 + i * 64;
      int c  = cb + lane;
      GLDS16(Ab + (c >> 2) * K + kt * 32 + (c & 3) * 8, As + cb * 8);
      GLDS16(Bb + (c >> 2) * K + kt * 32 + (c & 3) * 8, Bs + cb * 8);
    }
    __syncthreads();
    short8 af[4], bfv[4];
    const short8* Av = (const short8*)As;
    const short8* Bv = (const short8*)Bs;
#pragma unroll
    for (int i = 0; i < 4; i++) {
      af[i]  = Av[(wr * 64 + i * 16 + l15) * 4 + l4];
      bfv[i] = Bv[(wc * 64 + i * 16 + l15) * 4 + l4];
    }
#pragma unroll
    for (int m = 0; m < 4; m++)
#pragma unroll
      for (int n = 0; n < 4; n++)
        acc[m][n] = __builtin_amdgcn_mfma_f32_16x16x32_bf16(af[m], bfv[n], acc[m][n], 0, 0, 0);
    __syncthreads();
  }

#pragma unroll
  for (int m = 0; m < 4; m++) {
#pragma unroll
    for (int n = 0; n < 4; n++) {
      int col = colBase + wc * 64 + n * 16 + l15;
      float bs = bias[col];
      int row0 = rowBase + wr * 64 + m * 16 + l4 * 4;
#pragma unroll
      for (int j = 0; j < 4; j++) {
        float val = acc[m][n][j] + bs;
        int row = row0 + j;
        if (EPI == 0) {
          int which = col / D;
          int r2 = col - which * D;
          int hh = r2 / HD, d = r2 - hh * HD;
          O[(size_t)((which * H + hh) * S + row) * HD + d] = __float2bfloat16(val);
        } else if (EPI == 1) {
          X[(size_t)row * N + col] += val;
        } else {
          float gl = 0.5f * val * (1.0f + erff(val * 0.70710678118654752f));
          O[(size_t)row * N + col] = __float2bfloat16(gl);
        }
      }
    }
  }
}

// ---------------- flash attention: QTILE=128, KTILE=64, 4 waves ----------------
__global__ __launch_bounds__(256) void flash_k(const bf16* __restrict__ q,
                                               const bf16* __restrict__ k,
                                               const bf16* __restrict__ vt,
                                               bf16* __restrict__ o) {
  __shared__ __align__(16) bf16 Qs[128 * 80];
  __shared__ __align__(16) bf16 Ks[64 * 80];
  __shared__ __align__(16) bf16 Vts[80 * 64];   // [hd][key], source-swizzled
  __shared__ __align__(16) bf16 Ps[128 * 72];   // padded stride 72
  const float scale = 0.11180339887498949f;     // 80^-0.5
  int tid = threadIdx.x, lane = tid & 63, wid = tid >> 6;
  int l15 = lane & 15, l4 = lane >> 4;
  int hh = blockIdx.y, qb = blockIdx.x * 128;

  const bf16* qg = q + (size_t)(hh * S + qb) * HD;
#pragma unroll
  for (int i = 0; i < 5; i++) {
    int cb = i * 256 + wid * 64;
    GLDS16(qg + (size_t)(cb + lane) * 8, Qs + cb * 8);
  }

  f32x4 oacc[2][5] = {};
  float mst[2][4], lst[2][4];
#pragma unroll
  for (int m = 0; m < 2; m++)
#pragma unroll
    for (int j = 0; j < 4; j++) { mst[m][j] = -3.0e38f; lst[m][j] = 0.f; }

  const short8 zero8 = {0, 0, 0, 0, 0, 0, 0, 0};
  __syncthreads();

  for (int kt = 0; kt < S / 64; kt++) {
    const bf16* kg = k + (size_t)(hh * S + kt * 64) * HD;   // contiguous 64 rows
    const bf16* vg = vt + (size_t)hh * HD * S + kt * 64;
#pragma unroll
    for (int i = 0; i < 2; i++) {
      int cb = i * 256 + wid * 64;
      int c  = cb + lane;
      GLDS16(kg + c * 8, Ks + cb * 8);
      int hd = c >> 3, cc = (c & 7) ^ (hd & 7);               // XOR source swizzle
      GLDS16(vg + hd * S + cc * 8, Vts + cb * 8);
    }
    if (wid < 2) {
      int cb = 512 + wid * 64;
      int c  = cb + lane;
      GLDS16(kg + c * 8, Ks + cb * 8);
      int hd = c >> 3, cc = (c & 7) ^ (hd & 7);
      GLDS16(vg + hd * S + cc * 8, Vts + cb * 8);
    }
    __syncthreads();

    // ---- QK^T (K-dim 80 = 32+32+16, tail predicated to zero) ----
    f32x4 sacc[2][4] = {};
#pragma unroll
    for (int kf = 0; kf < 3; kf++) {
      bool act = (kf < 2) || (l4 < 2);
      short8 aq[2], bk[4];
#pragma unroll
      for (int m = 0; m < 2; m++)
        aq[m] = act ? *(const short8*)&Qs[(wid * 32 + m * 16 + l15) * 80 + (kf * 4 + l4) * 8] : zero8;
#pragma unroll
      for (int n = 0; n < 4; n++)
        bk[n] = act ? *(const short8*)&Ks[(n * 16 + l15) * 80 + (kf * 4 + l4) * 8] : zero8;
#pragma unroll
      for (int m = 0; m < 2; m++)
#pragma unroll
        for (int n = 0; n < 4; n++)
          sacc[m][n] = __builtin_amdgcn_mfma_f32_16x16x32_bf16(aq[m], bk[n], sacc[m][n], 0, 0, 0);
    }

    // ---- online softmax ----
#pragma unroll
    for (int m = 0; m < 2; m++) {
#pragma unroll
      for (int j = 0; j < 4; j++) {
        float s0 = sacc[m][0][j] * scale, s1 = sacc[m][1][j] * scale;
        float s2 = sacc[m][2][j] * scale, s3 = sacc[m][3][j] * scale;
        float mx = fmaxf(fmaxf(s0, s1), fmaxf(s2, s3));
        mx = fmaxf(mx, __shfl_xor(mx, 1));
        mx = fmaxf(mx, __shfl_xor(mx, 2));
        mx = fmaxf(mx, __shfl_xor(mx, 4));
        mx = fmaxf(mx, __shfl_xor(mx, 8));
        float newm = fmaxf(mst[m][j], mx);
        float fac = __expf(mst[m][j] - newm);
        mst[m][j] = newm;
        float p0 = __expf(s0 - newm), p1 = __expf(s1 - newm);
        float p2 = __expf(s2 - newm), p3 = __expf(s3 - newm);
        int prow = wid * 32 + m * 16 + l4 * 4 + j;
        Ps[prow * 72 +      l15] = __float2bfloat16(p0);
        Ps[prow * 72 + 16 + l15] = __float2bfloat16(p1);
        Ps[prow * 72 + 32 + l15] = __float2bfloat16(p2);
        Ps[prow * 72 + 48 + l15] = __float2bfloat16(p3);
        float ps = p0 + p1 + p2 + p3;
        ps += __shfl_xor(ps, 1);
        ps += __shfl_xor(ps, 2);
        ps += __shfl_xor(ps, 4);
        ps += __shfl_xor(ps, 8);
        lst[m][j] = lst[m][j] * fac + ps;
#pragma unroll
        for (int n5 = 0; n5 < 5; n5++) oacc[m][n5][j] *= fac;
      }
    }

    // ---- PV ----
#pragma unroll
    for (int kf = 0; kf < 2; kf++) {
      short8 ap[2], bv[5];
#pragma unroll
      for (int m = 0; m < 2; m++)
        ap[m] = *(const short8*)&Ps[(wid * 32 + m * 16 + l15) * 72 + (kf * 4 + l4) * 8];
#pragma unroll
      for (int n5 = 0; n5 < 5; n5++) {
        int hd = n5 * 16 + l15;
        int cc = (kf * 4 + l4) ^ (hd & 7);
        bv[n5] = *(const short8*)&Vts[hd * 64 + cc * 8];
      }
#pragma unroll
      for (int m = 0; m < 2; m++)
#pragma unroll
        for (int n5 = 0; n5 < 5; n5++)
          oacc[m][n5] = __builtin_amdgcn_mfma_f32_16x16x32_bf16(ap[m], bv[n5], oacc[m][n5], 0, 0, 0);
    }
    __syncthreads();
  }

#pragma unroll
  for (int m = 0; m < 2; m++)
#pragma unroll
    for (int n5 = 0; n5 < 5; n5++)
#pragma unroll
      for (int j = 0; j < 4; j++) {
        int row = qb + wid * 32 + m * 16 + l4 * 4 + j;
        int col = hh * HD + n5 * 16 + l15;
        o[(size_t)row * D + col] = __float2bfloat16(oacc[m][n5][j] / lst[m][j]);
      }
}

extern "C" void kernel_launch(void* const* d_in, const int* in_sizes, int n_in,
                              void* d_out, int out_size, void* d_ws, size_t ws_size,
                              hipStream_t stream) {
  const float* hidden = (const float*)d_in[0];
  const float* cosp   = (const float*)d_in[1];
  const float* sinp   = (const float*)d_in[2];
  const float* qkv_w  = (const float*)d_in[3];
  const float* qkv_b  = (const float*)d_in[4];
  const float* proj_w = (const float*)d_in[5];
  const float* proj_b = (const float*)d_in[6];
  const float* ln1_g  = (const float*)d_in[7];
  const float* ln1_b  = (const float*)d_in[8];
  const float* ln2_g  = (const float*)d_in[9];
  const float* ln2_b  = (const float*)d_in[10];
  const float* fc1_w  = (const float*)d_in[11];
  const float* fc1_b  = (const float*)d_in[12];
  const float* fc2_w  = (const float*)d_in[13];
  const float* fc2_b  = (const float*)d_in[14];
  float* x = (float*)d_out;

  char* w = (char*)d_ws;
  auto alloc = [&](size_t bytes) { void* p = (void*)w; w += bytes; return p; };
  bf16* wqkvT = (bf16*)alloc((size_t)3 * D * D * 2);
  bf16* wprojT = (bf16*)alloc((size_t)D * D * 2);
  bf16* wfc1T = (bf16*)alloc((size_t)IM * D * 2);
  bf16* wfc2T = (bf16*)alloc((size_t)D * IM * 2);
  bf16* hbuf  = (bf16*)alloc((size_t)S * D * 2);
  bf16* qkvb  = (bf16*)alloc((size_t)3 * H * S * HD * 2);
  bf16* vtbuf = (bf16*)alloc((size_t)H * HD * S * 2);
  bf16* obuf  = (bf16*)alloc((size_t)S * D * 2);
  bf16* midb  = (bf16*)alloc((size_t)S * IM * 2);
  (void)ws_size; (void)in_sizes; (void)n_in; (void)out_size;

  hipMemcpyAsync(x, hidden, (size_t)S * D * sizeof(float), hipMemcpyDeviceToDevice, stream);

  for (int l = 0; l < 2; l++) {
    transpose_w<<<dim3(3 * D / 32, D / 32), 256, 0, stream>>>(qkv_w + (size_t)l * D * 3 * D, wqkvT, D, 3 * D);
    transpose_w<<<dim3(D / 32, D / 32), 256, 0, stream>>>(proj_w + (size_t)l * D * D, wprojT, D, D);
    transpose_w<<<dim3(IM / 32, D / 32), 256, 0, stream>>>(fc1_w + (size_t)l * D * IM, wfc1T, D, IM);
    transpose_w<<<dim3(D / 32, IM / 32), 256, 0, stream>>>(fc2_w + (size_t)l * IM * D, wfc2T, IM, D);

    layernorm_k<<<S, 256, 0, stream>>>(x, ln1_g + l * D, ln1_b + l * D, hbuf);
    gemm_bt<0, 3 * D, D><<<dim3(3 * D / 128, S / 128), 256, 0, stream>>>(
        hbuf, wqkvT, qkv_b + (size_t)l * 3 * D, nullptr, qkvb);
    rope_k<<<(2 * H * S * (HD / 2)) / 256, 256, 0, stream>>>(
        qkvb, qkvb + (size_t)H * S * HD, cosp, sinp);
    transpose_v<<<dim3(S / 16, HD / 16, H), 256, 0, stream>>>(qkvb + (size_t)2 * H * S * HD, vtbuf);
    flash_k<<<dim3(S / 128, H), 256, 0, stream>>>(
        qkvb, qkvb + (size_t)H * S * HD, vtbuf, obuf);
    gemm_bt<1, D, D><<<dim3(D / 128, S / 128), 256, 0, stream>>>(
        obuf, wprojT, proj_b + l * D, x, nullptr);

    layernorm_k<<<S, 256, 0, stream>>>(x, ln2_g + l * D, ln2_b + l * D, hbuf);
    gemm_bt<2, IM, D><<<dim3(IM / 128, S / 128), 256, 0, stream>>>(
        hbuf, wfc1T, fc1_b + (size_t)l * IM, nullptr, midb);
    gemm_bt<1, D, IM><<<dim3(D / 128, S / 128), 256, 0, stream>>>(
        midb, wfc2T, fc2_b + l * D, x, nullptr);
  }
}

// Round 3
// 802.252 us; speedup vs baseline: 1.0996x; 1.0996x over previous
//
#include <hip/hip_runtime.h>
#include <hip/hip_bf16.h>

using bf16 = __hip_bfloat16;
using short8 = __attribute__((ext_vector_type(8))) short;
using f32x4  = __attribute__((ext_vector_type(4))) float;

#define GLDS16(g, l) __builtin_amdgcn_global_load_lds( \
    (const __attribute__((address_space(1))) void*)(g), \
    (__attribute__((address_space(3))) void*)(l), 16, 0, 0)

constexpr int S  = 2048;
constexpr int D  = 1280;
constexpr int H  = 16;
constexpr int HD = 80;
constexpr int IM = 5120;

// ---------------- weight transpose: fp32 [K][N] -> bf16 [N][K] ----------------
__global__ __launch_bounds__(256) void transpose_w(const float* __restrict__ W,
                                                   bf16* __restrict__ Wt,
                                                   int K, int N) {
  __shared__ float t[32][33];
  int tx = threadIdx.x & 31, ty = threadIdx.x >> 5;
  int n0 = blockIdx.x * 32, k0 = blockIdx.y * 32;
#pragma unroll
  for (int i = 0; i < 4; i++)
    t[ty + i * 8][tx] = W[(size_t)(k0 + ty + i * 8) * N + n0 + tx];
  __syncthreads();
#pragma unroll
  for (int i = 0; i < 4; i++)
    Wt[(size_t)(n0 + ty + i * 8) * K + k0 + tx] = __float2bfloat16(t[tx][ty + i * 8]);
}

// ---------------- V transpose: bf16 [H][S][HD] -> [H][HD][S] ----------------
__global__ __launch_bounds__(256) void transpose_v(const bf16* __restrict__ v,
                                                   bf16* __restrict__ vt) {
  __shared__ bf16 t[16][17];
  int tx = threadIdx.x & 15, ty = threadIdx.x >> 4;
  int s0 = blockIdx.x * 16, d0 = blockIdx.y * 16, h = blockIdx.z;
  t[ty][tx] = v[(size_t)(h * S + s0 + ty) * HD + d0 + tx];
  __syncthreads();
  vt[(size_t)(h * HD + d0 + ty) * S + s0 + tx] = t[tx][ty];
}

// ---------------- layernorm: fp32 x [S][D] -> bf16 h ----------------
__global__ __launch_bounds__(256) void layernorm_k(const float* __restrict__ x,
                                                   const float* __restrict__ g,
                                                   const float* __restrict__ b,
                                                   bf16* __restrict__ h) {
  int row = blockIdx.x, tid = threadIdx.x;
  const float* xr = x + (size_t)row * D;
  float v[5], s1 = 0.f, s2 = 0.f;
#pragma unroll
  for (int i = 0; i < 5; i++) {
    v[i] = xr[tid + i * 256];
    s1 += v[i]; s2 += v[i] * v[i];
  }
#pragma unroll
  for (int o = 32; o > 0; o >>= 1) {
    s1 += __shfl_down(s1, o);
    s2 += __shfl_down(s2, o);
  }
  __shared__ float r1[4], r2[4];
  if ((tid & 63) == 0) { r1[tid >> 6] = s1; r2[tid >> 6] = s2; }
  __syncthreads();
  s1 = r1[0] + r1[1] + r1[2] + r1[3];
  s2 = r2[0] + r2[1] + r2[2] + r2[3];
  float mean = s1 * (1.f / D);
  float rstd = rsqrtf(s2 * (1.f / D) - mean * mean + 1e-6f);
  bf16* hr = h + (size_t)row * D;
#pragma unroll
  for (int i = 0; i < 5; i++) {
    int c = tid + i * 256;
    hr[c] = __float2bfloat16((v[i] - mean) * rstd * g[c] + b[c]);
  }
}

// ---------------- RoPE (in-place on q,k [H][S][HD]) ----------------
__global__ __launch_bounds__(256) void rope_k(bf16* __restrict__ q, bf16* __restrict__ k,
                                              const float* __restrict__ cs,
                                              const float* __restrict__ sn) {
  int idx = blockIdx.x * 256 + threadIdx.x;   // 2*H*S*40 threads
  int p  = idx % 40;
  int t  = idx / 40;
  int s  = t & (S - 1);
  int t2 = t >> 11;
  int hh = t2 & (H - 1);
  bf16* base = ((t2 >> 4) ? k : q) + (size_t)(hh * S + s) * HD;
  float c0 = cs[s * HD + p],      s0 = sn[s * HD + p];
  float c1 = cs[s * HD + p + 40], s1 = sn[s * HD + p + 40];
  float x0 = __bfloat162float(base[p]);
  float x1 = __bfloat162float(base[p + 40]);
  base[p]      = __float2bfloat16(x0 * c0 - x1 * s0);
  base[p + 40] = __float2bfloat16(x1 * c1 + x0 * s1);
}

// ---------------- GEMM v2: 128x128 tile, BK=32, double-buffered 2-phase ----------------
// A[2048][K] x Bt[N][K] (+bias), LDS chunk-XOR swizzled (both sides).
// EPI 0: split into q/k/v buffers [3][H][S][HD] bf16
// EPI 1: residual add into fp32 X[2048][N]
// EPI 2: exact GELU -> bf16 O[2048][N]
// EPI 3: fp32 partial (no bias) into P[z][2048][N]  (split-K)
template <int EPI, int N, int K, int SPLITK>
__global__ __launch_bounds__(256, 2) void gemm2(const bf16* __restrict__ A,
                                                const bf16* __restrict__ Bt,
                                                const float* __restrict__ bias,
                                                float* __restrict__ X,
                                                bf16* __restrict__ O,
                                                float* __restrict__ P) {
  __shared__ __align__(16) short As[2][128 * 32];
  __shared__ __align__(16) short Bs[2][128 * 32];
  int tid = threadIdx.x, lane = tid & 63, wid = tid >> 6;
  int l15 = lane & 15, l4 = lane >> 4;
  int wr = wid >> 1, wc = wid & 1;

  // bijective XCD swizzle (m204) on linear block id (x-fastest order)
  int gx = gridDim.x;
  int nwg = gx * (int)gridDim.y;
  int lin = blockIdx.y * gx + blockIdx.x;
  int q = nwg >> 3, r = nwg & 7;
  int xcd = lin & 7, idx = lin >> 3;
  int swz = (xcd < r ? xcd * (q + 1) : r * (q + 1) + (xcd - r) * q) + idx;
  int bx = swz % gx, by = swz / gx;

  int rowBase = by * 128, colBase = bx * 128;
  constexpr int KS = K / SPLITK;
  constexpr int NT = KS / 32;
  int k0 = blockIdx.z * KS;
  const bf16* Ab = A  + (size_t)rowBase * K + k0;
  const bf16* Bb = Bt + (size_t)colBase * K + k0;

  f32x4 acc[4][4] = {};

  // staging: chunk c in [0,512): row=c>>2, ci=c&3, source chunk ci^((row>>1)&3)
  auto stage = [&](int buf, int kt) {
#pragma unroll
    for (int i = 0; i < 2; i++) {
      int cb = wid * 128 + i * 64;
      int c  = cb + lane;
      int row = c >> 2;
      int ci  = (c & 3) ^ ((row >> 1) & 3);
      GLDS16(Ab + (size_t)row * K + kt * 32 + ci * 8, &As[buf][cb * 8]);
      GLDS16(Bb + (size_t)row * K + kt * 32 + ci * 8, &Bs[buf][cb * 8]);
    }
  };

  stage(0, 0);
  __syncthreads();

  int cur = 0;
  for (int kt = 0; kt < NT; kt++) {
    if (kt + 1 < NT) stage(cur ^ 1, kt + 1);
    short8 af[4], bfv[4];
    const short8* Av = (const short8*)As[cur];
    const short8* Bv = (const short8*)Bs[cur];
#pragma unroll
    for (int i = 0; i < 4; i++) {
      int ra = wr * 64 + i * 16 + l15;
      int rb = wc * 64 + i * 16 + l15;
      af[i]  = Av[ra * 4 + (l4 ^ ((ra >> 1) & 3))];
      bfv[i] = Bv[rb * 4 + (l4 ^ ((rb >> 1) & 3))];
    }
#pragma unroll
    for (int m = 0; m < 4; m++)
#pragma unroll
      for (int n = 0; n < 4; n++)
        acc[m][n] = __builtin_amdgcn_mfma_f32_16x16x32_bf16(af[m], bfv[n], acc[m][n], 0, 0, 0);
    __syncthreads();
    cur ^= 1;
  }

#pragma unroll
  for (int m = 0; m < 4; m++) {
#pragma unroll
    for (int n = 0; n < 4; n++) {
      int col = colBase + wc * 64 + n * 16 + l15;
      float bs = (EPI == 3) ? 0.f : bias[col];
      int row0 = rowBase + wr * 64 + m * 16 + l4 * 4;
#pragma unroll
      for (int j = 0; j < 4; j++) {
        float val = acc[m][n][j] + bs;
        int row = row0 + j;
        if (EPI == 0) {
          int which = col / D;
          int r2 = col - which * D;
          int hh = r2 / HD, d = r2 - hh * HD;
          O[(size_t)((which * H + hh) * S + row) * HD + d] = __float2bfloat16(val);
        } else if (EPI == 1) {
          X[(size_t)row * N + col] += val;
        } else if (EPI == 2) {
          float gl = 0.5f * val * (1.0f + erff(val * 0.70710678118654752f));
          O[(size_t)row * N + col] = __float2bfloat16(gl);
        } else {
          P[(size_t)blockIdx.z * (2048 * N) + (size_t)row * N + col] = val;
        }
      }
    }
  }
}

// ---------------- split-K reduce: X += P0 + P1 + bias ----------------
__global__ __launch_bounds__(256) void reduce_add(const float* __restrict__ P,
                                                  const float* __restrict__ bias,
                                                  float* __restrict__ X) {
  int i = blockIdx.x * 1024 + threadIdx.x * 4;
  int col = i % D;
  float4 p0 = *(const float4*)&P[i];
  float4 p1 = *(const float4*)&P[(size_t)2048 * D + i];
  float4 bv = *(const float4*)&bias[col];
  float4 xv = *(const float4*)&X[i];
  xv.x += p0.x + p1.x + bv.x;
  xv.y += p0.y + p1.y + bv.y;
  xv.z += p0.z + p1.z + bv.z;
  xv.w += p0.w + p1.w + bv.w;
  *(float4*)&X[i] = xv;
}

// ---------------- flash attention: QTILE=128, KTILE=64, 4 waves ----------------
__global__ __launch_bounds__(256) void flash_k(const bf16* __restrict__ q,
                                               const bf16* __restrict__ k,
                                               const bf16* __restrict__ vt,
                                               bf16* __restrict__ o) {
  __shared__ __align__(16) bf16 Qs[128 * 80];
  __shared__ __align__(16) bf16 Ks[64 * 80];
  __shared__ __align__(16) bf16 Vts[80 * 64];   // [hd][key], source-swizzled
  __shared__ __align__(16) bf16 Ps[128 * 72];   // padded stride 72
  const float scale = 0.11180339887498949f;     // 80^-0.5
  int tid = threadIdx.x, lane = tid & 63, wid = tid >> 6;
  int l15 = lane & 15, l4 = lane >> 4;
  int hh = blockIdx.y, qb = blockIdx.x * 128;

  const bf16* qg = q + (size_t)(hh * S + qb) * HD;
#pragma unroll
  for (int i = 0; i < 5; i++) {
    int cb = i * 256 + wid * 64;
    GLDS16(qg + (size_t)(cb + lane) * 8, Qs + cb * 8);
  }

  f32x4 oacc[2][5] = {};
  float mst[2][4], lst[2][4];
#pragma unroll
  for (int m = 0; m < 2; m++)
#pragma unroll
    for (int j = 0; j < 4; j++) { mst[m][j] = -3.0e38f; lst[m][j] = 0.f; }

  const short8 zero8 = {0, 0, 0, 0, 0, 0, 0, 0};
  __syncthreads();

  for (int kt = 0; kt < S / 64; kt++) {
    const bf16* kg = k + (size_t)(hh * S + kt * 64) * HD;   // contiguous 64 rows
    const bf16* vg = vt + (size_t)hh * HD * S + kt * 64;
#pragma unroll
    for (int i = 0; i < 2; i++) {
      int cb = i * 256 + wid * 64;
      int c  = cb + lane;
      GLDS16(kg + c * 8, Ks + cb * 8);
      int hd = c >> 3, cc = (c & 7) ^ (hd & 7);               // XOR source swizzle
      GLDS16(vg + hd * S + cc * 8, Vts + cb * 8);
    }
    if (wid < 2) {
      int cb = 512 + wid * 64;
      int c  = cb + lane;
      GLDS16(kg + c * 8, Ks + cb * 8);
      int hd = c >> 3, cc = (c & 7) ^ (hd & 7);
      GLDS16(vg + hd * S + cc * 8, Vts + cb * 8);
    }
    __syncthreads();

    // ---- QK^T (K-dim 80 = 32+32+16, tail predicated to zero) ----
    f32x4 sacc[2][4] = {};
#pragma unroll
    for (int kf = 0; kf < 3; kf++) {
      bool act = (kf < 2) || (l4 < 2);
      short8 aq[2], bk[4];
#pragma unroll
      for (int m = 0; m < 2; m++)
        aq[m] = act ? *(const short8*)&Qs[(wid * 32 + m * 16 + l15) * 80 + (kf * 4 + l4) * 8] : zero8;
#pragma unroll
      for (int n = 0; n < 4; n++)
        bk[n] = act ? *(const short8*)&Ks[(n * 16 + l15) * 80 + (kf * 4 + l4) * 8] : zero8;
#pragma unroll
      for (int m = 0; m < 2; m++)
#pragma unroll
        for (int n = 0; n < 4; n++)
          sacc[m][n] = __builtin_amdgcn_mfma_f32_16x16x32_bf16(aq[m], bk[n], sacc[m][n], 0, 0, 0);
    }

    // ---- online softmax ----
#pragma unroll
    for (int m = 0; m < 2; m++) {
#pragma unroll
      for (int j = 0; j < 4; j++) {
        float s0 = sacc[m][0][j] * scale, s1 = sacc[m][1][j] * scale;
        float s2 = sacc[m][2][j] * scale, s3 = sacc[m][3][j] * scale;
        float mx = fmaxf(fmaxf(s0, s1), fmaxf(s2, s3));
        mx = fmaxf(mx, __shfl_xor(mx, 1));
        mx = fmaxf(mx, __shfl_xor(mx, 2));
        mx = fmaxf(mx, __shfl_xor(mx, 4));
        mx = fmaxf(mx, __shfl_xor(mx, 8));
        float newm = fmaxf(mst[m][j], mx);
        float fac = __expf(mst[m][j] - newm);
        mst[m][j] = newm;
        float p0 = __expf(s0 - newm), p1 = __expf(s1 - newm);
        float p2 = __expf(s2 - newm), p3 = __expf(s3 - newm);
        int prow = wid * 32 + m * 16 + l4 * 4 + j;
        Ps[prow * 72 +      l15] = __float2bfloat16(p0);
        Ps[prow * 72 + 16 + l15] = __float2bfloat16(p1);
        Ps[prow * 72 + 32 + l15] = __float2bfloat16(p2);
        Ps[prow * 72 + 48 + l15] = __float2bfloat16(p3);
        float ps = p0 + p1 + p2 + p3;
        ps += __shfl_xor(ps, 1);
        ps += __shfl_xor(ps, 2);
        ps += __shfl_xor(ps, 4);
        ps += __shfl_xor(ps, 8);
        lst[m][j] = lst[m][j] * fac + ps;
#pragma unroll
        for (int n5 = 0; n5 < 5; n5++) oacc[m][n5][j] *= fac;
      }
    }

    // ---- PV ----
#pragma unroll
    for (int kf = 0; kf < 2; kf++) {
      short8 ap[2], bv[5];
#pragma unroll
      for (int m = 0; m < 2; m++)
        ap[m] = *(const short8*)&Ps[(wid * 32 + m * 16 + l15) * 72 + (kf * 4 + l4) * 8];
#pragma unroll
      for (int n5 = 0; n5 < 5; n5++) {
        int hd = n5 * 16 + l15;
        int cc = (kf * 4 + l4) ^ (hd & 7);
        bv[n5] = *(const short8*)&Vts[hd * 64 + cc * 8];
      }
#pragma unroll
      for (int m = 0; m < 2; m++)
#pragma unroll
        for (int n5 = 0; n5 < 5; n5++)
          oacc[m][n5] = __builtin_amdgcn_mfma_f32_16x16x32_bf16(ap[m], bv[n5], oacc[m][n5], 0, 0, 0);
    }
    __syncthreads();
  }

#pragma unroll
  for (int m = 0; m < 2; m++)
#pragma unroll
    for (int n5 = 0; n5 < 5; n5++)
#pragma unroll
      for (int j = 0; j < 4; j++) {
        int row = qb + wid * 32 + m * 16 + l4 * 4 + j;
        int col = hh * HD + n5 * 16 + l15;
        o[(size_t)row * D + col] = __float2bfloat16(oacc[m][n5][j] / lst[m][j]);
      }
}

extern "C" void kernel_launch(void* const* d_in, const int* in_sizes, int n_in,
                              void* d_out, int out_size, void* d_ws, size_t ws_size,
                              hipStream_t stream) {
  const float* hidden = (const float*)d_in[0];
  const float* cosp   = (const float*)d_in[1];
  const float* sinp   = (const float*)d_in[2];
  const float* qkv_w  = (const float*)d_in[3];
  const float* qkv_b  = (const float*)d_in[4];
  const float* proj_w = (const float*)d_in[5];
  const float* proj_b = (const float*)d_in[6];
  const float* ln1_g  = (const float*)d_in[7];
  const float* ln1_b  = (const float*)d_in[8];
  const float* ln2_g  = (const float*)d_in[9];
  const float* ln2_b  = (const float*)d_in[10];
  const float* fc1_w  = (const float*)d_in[11];
  const float* fc1_b  = (const float*)d_in[12];
  const float* fc2_w  = (const float*)d_in[13];
  const float* fc2_b  = (const float*)d_in[14];
  float* x = (float*)d_out;

  char* w = (char*)d_ws;
  auto alloc = [&](size_t bytes) { void* p = (void*)w; w += bytes; return p; };
  bf16* wqkvT  = (bf16*)alloc((size_t)3 * D * D * 2);
  bf16* wprojT = (bf16*)alloc((size_t)D * D * 2);
  bf16* wfc1T  = (bf16*)alloc((size_t)IM * D * 2);
  bf16* wfc2T  = (bf16*)alloc((size_t)D * IM * 2);
  bf16* hbuf   = (bf16*)alloc((size_t)S * D * 2);
  bf16* qkvb   = (bf16*)alloc((size_t)3 * H * S * HD * 2);   // } contiguous:
  bf16* vtbuf  = (bf16*)alloc((size_t)H * HD * S * 2);       // } FC2 partial alias (21.0 MB)
  bf16* obuf   = (bf16*)alloc((size_t)S * D * 2);
  bf16* midb   = (bf16*)alloc((size_t)S * IM * 2);           // proj partial alias (21.0 MB)
  float* Pproj = (float*)midb;   // dead during proj gemm+reduce
  float* Pfc2  = (float*)qkvb;   // qkvb+vtbuf dead after flash; 2*2048*1280*4 == their size
  (void)ws_size; (void)in_sizes; (void)n_in; (void)out_size;

  hipMemcpyAsync(x, hidden, (size_t)S * D * sizeof(float), hipMemcpyDeviceToDevice, stream);

  for (int l = 0; l < 2; l++) {
    transpose_w<<<dim3(3 * D / 32, D / 32), 256, 0, stream>>>(qkv_w + (size_t)l * D * 3 * D, wqkvT, D, 3 * D);
    transpose_w<<<dim3(D / 32, D / 32), 256, 0, stream>>>(proj_w + (size_t)l * D * D, wprojT, D, D);
    transpose_w<<<dim3(IM / 32, D / 32), 256, 0, stream>>>(fc1_w + (size_t)l * D * IM, wfc1T, D, IM);
    transpose_w<<<dim3(D / 32, IM / 32), 256, 0, stream>>>(fc2_w + (size_t)l * IM * D, wfc2T, IM, D);

    layernorm_k<<<S, 256, 0, stream>>>(x, ln1_g + l * D, ln1_b + l * D, hbuf);
    gemm2<0, 3 * D, D, 1><<<dim3(3 * D / 128, S / 128, 1), 256, 0, stream>>>(
        hbuf, wqkvT, qkv_b + (size_t)l * 3 * D, nullptr, qkvb, nullptr);
    rope_k<<<(2 * H * S * (HD / 2)) / 256, 256, 0, stream>>>(
        qkvb, qkvb + (size_t)H * S * HD, cosp, sinp);
    transpose_v<<<dim3(S / 16, HD / 16, H), 256, 0, stream>>>(qkvb + (size_t)2 * H * S * HD, vtbuf);
    flash_k<<<dim3(S / 128, H), 256, 0, stream>>>(
        qkvb, qkvb + (size_t)H * S * HD, vtbuf, obuf);
    gemm2<3, D, D, 2><<<dim3(D / 128, S / 128, 2), 256, 0, stream>>>(
        obuf, wprojT, nullptr, nullptr, nullptr, Pproj);
    reduce_add<<<(S * D) / 1024, 256, 0, stream>>>(Pproj, proj_b + l * D, x);

    layernorm_k<<<S, 256, 0, stream>>>(x, ln2_g + l * D, ln2_b + l * D, hbuf);
    gemm2<2, IM, D, 1><<<dim3(IM / 128, S / 128, 1), 256, 0, stream>>>(
        hbuf, wfc1T, fc1_b + (size_t)l * IM, nullptr, midb, nullptr);
    gemm2<3, D, IM, 2><<<dim3(D / 128, S / 128, 2), 256, 0, stream>>>(
        midb, wfc2T, nullptr, nullptr, nullptr, Pfc2);
    reduce_add<<<(S * D) / 1024, 256, 0, stream>>>(Pfc2, fc2_b + l * D, x);
  }
}

// Round 7
// 758.913 us; speedup vs baseline: 1.1624x; 1.0571x over previous
//
#include <hip/hip_runtime.h>
#include <hip/hip_bf16.h>

using bf16 = __hip_bfloat16;
using short8 = __attribute__((ext_vector_type(8))) short;
using f32x4  = __attribute__((ext_vector_type(4))) float;

#define GLDS16(g, l) __builtin_amdgcn_global_load_lds( \
    (const __attribute__((address_space(1))) void*)(g), \
    (__attribute__((address_space(3))) void*)(l), 16, 0, 0)

constexpr int S  = 2048;
constexpr int D  = 1280;
constexpr int H  = 16;
constexpr int HD = 80;
constexpr int IM = 5120;

// ---------------- weight transpose: fp32 [K][N] -> bf16 [N][K] ----------------
__global__ __launch_bounds__(256) void transpose_w(const float* __restrict__ W,
                                                   bf16* __restrict__ Wt,
                                                   int K, int N) {
  __shared__ float t[32][33];
  int tx = threadIdx.x & 31, ty = threadIdx.x >> 5;
  int n0 = blockIdx.x * 32, k0 = blockIdx.y * 32;
#pragma unroll
  for (int i = 0; i < 4; i++)
    t[ty + i * 8][tx] = W[(size_t)(k0 + ty + i * 8) * N + n0 + tx];
  __syncthreads();
#pragma unroll
  for (int i = 0; i < 4; i++)
    Wt[(size_t)(n0 + ty + i * 8) * K + k0 + tx] = __float2bfloat16(t[tx][ty + i * 8]);
}

// ---------------- V transpose: bf16 [H][S][HD] -> [H][HD][S] ----------------
__global__ __launch_bounds__(256) void transpose_v(const bf16* __restrict__ v,
                                                   bf16* __restrict__ vt) {
  __shared__ bf16 t[16][17];
  int tx = threadIdx.x & 15, ty = threadIdx.x >> 4;
  int s0 = blockIdx.x * 16, d0 = blockIdx.y * 16, h = blockIdx.z;
  t[ty][tx] = v[(size_t)(h * S + s0 + ty) * HD + d0 + tx];
  __syncthreads();
  vt[(size_t)(h * HD + d0 + ty) * S + s0 + tx] = t[tx][ty];
}

// ---------------- layernorm: fp32 x [S][D] -> bf16 h ----------------
__global__ __launch_bounds__(256) void layernorm_k(const float* __restrict__ x,
                                                   const float* __restrict__ g,
                                                   const float* __restrict__ b,
                                                   bf16* __restrict__ h) {
  int row = blockIdx.x, tid = threadIdx.x;
  const float* xr = x + (size_t)row * D;
  float v[5], s1 = 0.f, s2 = 0.f;
#pragma unroll
  for (int i = 0; i < 5; i++) {
    v[i] = xr[tid + i * 256];
    s1 += v[i]; s2 += v[i] * v[i];
  }
#pragma unroll
  for (int o = 32; o > 0; o >>= 1) {
    s1 += __shfl_down(s1, o);
    s2 += __shfl_down(s2, o);
  }
  __shared__ float r1[4], r2[4];
  if ((tid & 63) == 0) { r1[tid >> 6] = s1; r2[tid >> 6] = s2; }
  __syncthreads();
  s1 = r1[0] + r1[1] + r1[2] + r1[3];
  s2 = r2[0] + r2[1] + r2[2] + r2[3];
  float mean = s1 * (1.f / D);
  float rstd = rsqrtf(s2 * (1.f / D) - mean * mean + 1e-6f);
  bf16* hr = h + (size_t)row * D;
#pragma unroll
  for (int i = 0; i < 5; i++) {
    int c = tid + i * 256;
    hr[c] = __float2bfloat16((v[i] - mean) * rstd * g[c] + b[c]);
  }
}

// ---------------- RoPE (in-place on q,k [H][S][HD]) ----------------
__global__ __launch_bounds__(256) void rope_k(bf16* __restrict__ q, bf16* __restrict__ k,
                                              const float* __restrict__ cs,
                                              const float* __restrict__ sn) {
  int idx = blockIdx.x * 256 + threadIdx.x;   // 2*H*S*40 threads
  int p  = idx % 40;
  int t  = idx / 40;
  int s  = t & (S - 1);
  int t2 = t >> 11;
  int hh = t2 & (H - 1);
  bf16* base = ((t2 >> 4) ? k : q) + (size_t)(hh * S + s) * HD;
  float c0 = cs[s * HD + p],      s0 = sn[s * HD + p];
  float c1 = cs[s * HD + p + 40], s1 = sn[s * HD + p + 40];
  float x0 = __bfloat162float(base[p]);
  float x1 = __bfloat162float(base[p + 40]);
  base[p]      = __float2bfloat16(x0 * c0 - x1 * s0);
  base[p + 40] = __float2bfloat16(x1 * c1 + x0 * s1);
}

// ---------------- GEMM v2: 128x128 tile, BK=32, double-buffered 2-phase ----------------
// A[2048][K] x Bt[N][K] (+bias), LDS chunk-XOR swizzled (both sides).
// EPI 0: split into q/k/v buffers [3][H][S][HD] bf16
// EPI 1: residual add into fp32 X[2048][N]
// EPI 2: exact GELU -> bf16 O[2048][N]
// EPI 3: fp32 partial (no bias) into P[z][2048][N]  (split-K)
template <int EPI, int N, int K, int SPLITK>
__global__ __launch_bounds__(256, 2) void gemm2(const bf16* __restrict__ A,
                                                const bf16* __restrict__ Bt,
                                                const float* __restrict__ bias,
                                                float* __restrict__ X,
                                                bf16* __restrict__ O,
                                                float* __restrict__ P) {
  __shared__ __align__(16) short As[2][128 * 32];
  __shared__ __align__(16) short Bs[2][128 * 32];
  int tid = threadIdx.x, lane = tid & 63, wid = tid >> 6;
  int l15 = lane & 15, l4 = lane >> 4;
  int wr = wid >> 1, wc = wid & 1;

  // bijective XCD swizzle (m204) on linear block id (x-fastest order)
  int gx = gridDim.x;
  int nwg = gx * (int)gridDim.y;
  int lin = blockIdx.y * gx + blockIdx.x;
  int q = nwg >> 3, r = nwg & 7;
  int xcd = lin & 7, idx = lin >> 3;
  int swz = (xcd < r ? xcd * (q + 1) : r * (q + 1) + (xcd - r) * q) + idx;
  int bx = swz % gx, by = swz / gx;

  int rowBase = by * 128, colBase = bx * 128;
  constexpr int KS = K / SPLITK;
  constexpr int NT = KS / 32;
  int k0 = blockIdx.z * KS;
  const bf16* Ab = A  + (size_t)rowBase * K + k0;
  const bf16* Bb = Bt + (size_t)colBase * K + k0;

  f32x4 acc[4][4] = {};

  // staging: chunk c in [0,512): row=c>>2, ci=c&3, source chunk ci^((row>>1)&3)
  auto stage = [&](int buf, int kt) {
#pragma unroll
    for (int i = 0; i < 2; i++) {
      int cb = wid * 128 + i * 64;
      int c  = cb + lane;
      int row = c >> 2;
      int ci  = (c & 3) ^ ((row >> 1) & 3);
      GLDS16(Ab + (size_t)row * K + kt * 32 + ci * 8, &As[buf][cb * 8]);
      GLDS16(Bb + (size_t)row * K + kt * 32 + ci * 8, &Bs[buf][cb * 8]);
    }
  };

  stage(0, 0);
  __syncthreads();

  int cur = 0;
  for (int kt = 0; kt < NT; kt++) {
    if (kt + 1 < NT) stage(cur ^ 1, kt + 1);
    short8 af[4], bfv[4];
    const short8* Av = (const short8*)As[cur];
    const short8* Bv = (const short8*)Bs[cur];
#pragma unroll
    for (int i = 0; i < 4; i++) {
      int ra = wr * 64 + i * 16 + l15;
      int rb = wc * 64 + i * 16 + l15;
      af[i]  = Av[ra * 4 + (l4 ^ ((ra >> 1) & 3))];
      bfv[i] = Bv[rb * 4 + (l4 ^ ((rb >> 1) & 3))];
    }
#pragma unroll
    for (int m = 0; m < 4; m++)
#pragma unroll
      for (int n = 0; n < 4; n++)
        acc[m][n] = __builtin_amdgcn_mfma_f32_16x16x32_bf16(af[m], bfv[n], acc[m][n], 0, 0, 0);
    __syncthreads();
    cur ^= 1;
  }

#pragma unroll
  for (int m = 0; m < 4; m++) {
#pragma unroll
    for (int n = 0; n < 4; n++) {
      int col = colBase + wc * 64 + n * 16 + l15;
      float bs = (EPI == 3) ? 0.f : bias[col];
      int row0 = rowBase + wr * 64 + m * 16 + l4 * 4;
#pragma unroll
      for (int j = 0; j < 4; j++) {
        float val = acc[m][n][j] + bs;
        int row = row0 + j;
        if (EPI == 0) {
          int which = col / D;
          int r2 = col - which * D;
          int hh = r2 / HD, d = r2 - hh * HD;
          O[(size_t)((which * H + hh) * S + row) * HD + d] = __float2bfloat16(val);
        } else if (EPI == 1) {
          X[(size_t)row * N + col] += val;
        } else if (EPI == 2) {
          float gl = 0.5f * val * (1.0f + erff(val * 0.70710678118654752f));
          O[(size_t)row * N + col] = __float2bfloat16(gl);
        } else {
          P[(size_t)blockIdx.z * (2048 * N) + (size_t)row * N + col] = val;
        }
      }
    }
  }
}

// ---------------- split-K reduce: X += P0 + P1 + bias ----------------
__global__ __launch_bounds__(256) void reduce_add(const float* __restrict__ P,
                                                  const float* __restrict__ bias,
                                                  float* __restrict__ X) {
  int i = blockIdx.x * 1024 + threadIdx.x * 4;
  int col = i % D;
  float4 p0 = *(const float4*)&P[i];
  float4 p1 = *(const float4*)&P[(size_t)2048 * D + i];
  float4 bv = *(const float4*)&bias[col];
  float4 xv = *(const float4*)&X[i];
  xv.x += p0.x + p1.x + bv.x;
  xv.y += p0.y + p1.y + bv.y;
  xv.z += p0.z + p1.z + bv.z;
  xv.w += p0.w + p1.w + bv.w;
  *(float4*)&X[i] = xv;
}

// ---------------- flash attention v2: QTILE=64, KTILE=64, 4 waves, dbuf KV ----------------
__global__ __launch_bounds__(256) void flash_k(const bf16* __restrict__ q,
                                               const bf16* __restrict__ k,
                                               const bf16* __restrict__ vt,
                                               bf16* __restrict__ o) {
  __shared__ __align__(16) bf16 Qs[64 * 80];
  __shared__ __align__(16) bf16 Ks[2][64 * 80];
  __shared__ __align__(16) bf16 Vts[2][80 * 64];  // [hd][key], source-swizzled
  __shared__ __align__(16) bf16 Ps[64 * 72];      // padded stride 72
  const float scale = 0.11180339887498949f;       // 80^-0.5
  int tid = threadIdx.x, lane = tid & 63, wid = tid >> 6;
  int l15 = lane & 15, l4 = lane >> 4;

  // XCD-grouping swizzle: 512 blocks, bijective (lin>>3, lin&7) -> (lin&7)*64 + lin>>3
  // (head h occupies swz range [h*32, h*32+32) -> ~half a head per XCD -> K/V L2-resident)
  int lin = blockIdx.y * 32 + blockIdx.x;
  int swz = (lin & 7) * 64 + (lin >> 3);
  int hh = swz >> 5, qb = (swz & 31) * 64;

  // ---- stage Q: 64 rows x 80 bf16 = 640 16-B chunks (2x256 + 2x64 tail) ----
  const bf16* qg = q + (size_t)(hh * S + qb) * HD;
#pragma unroll
  for (int i = 0; i < 2; i++) {
    int cb = i * 256 + wid * 64;
    GLDS16(qg + (size_t)(cb + lane) * 8, Qs + cb * 8);
  }
  if (wid < 2) {
    int cb = 512 + wid * 64;
    GLDS16(qg + (size_t)(cb + lane) * 8, Qs + cb * 8);
  }

  auto stage_kv = [&](int buf, int kt) {
    const bf16* kg = k + (size_t)(hh * S + kt * 64) * HD;
    const bf16* vg = vt + (size_t)hh * HD * S + kt * 64;
#pragma unroll
    for (int i = 0; i < 2; i++) {
      int cb = i * 256 + wid * 64;
      int c  = cb + lane;
      GLDS16(kg + (size_t)c * 8, &Ks[buf][cb * 8]);
      int hd = c >> 3, ci = (c & 7) ^ (hd & 7);     // XOR source swizzle
      GLDS16(vg + (size_t)hd * S + ci * 8, &Vts[buf][cb * 8]);
    }
    if (wid < 2) {
      int cb = 512 + wid * 64;
      int c  = cb + lane;
      GLDS16(kg + (size_t)c * 8, &Ks[buf][cb * 8]);
      int hd = c >> 3, ci = (c & 7) ^ (hd & 7);
      GLDS16(vg + (size_t)hd * S + ci * 8, &Vts[buf][cb * 8]);
    }
  };

  f32x4 oacc[5] = {};
  float mst[4], lst[4];
#pragma unroll
  for (int j = 0; j < 4; j++) { mst[j] = -3.0e38f; lst[j] = 0.f; }
  const short8 zero8 = {0, 0, 0, 0, 0, 0, 0, 0};

  stage_kv(0, 0);
  __syncthreads();

  int cur = 0;
  for (int kt = 0; kt < S / 64; kt++) {
    if (kt + 1 < S / 64) stage_kv(cur ^ 1, kt + 1);   // prefetch hides under compute

    // ---- QK^T (K-dim 80 = 32+32+16, tail predicated to zero) ----
    f32x4 sacc[4] = {};
#pragma unroll
    for (int kf = 0; kf < 3; kf++) {
      bool act = (kf < 2) || (l4 < 2);
      short8 aq = act ? *(const short8*)&Qs[(wid * 16 + l15) * 80 + (kf * 4 + l4) * 8] : zero8;
#pragma unroll
      for (int n = 0; n < 4; n++) {
        short8 bk = act ? *(const short8*)&Ks[cur][(n * 16 + l15) * 80 + (kf * 4 + l4) * 8] : zero8;
        sacc[n] = __builtin_amdgcn_mfma_f32_16x16x32_bf16(aq, bk, sacc[n], 0, 0, 0);
      }
    }

    // ---- online softmax ----
#pragma unroll
    for (int j = 0; j < 4; j++) {
      float s0 = sacc[0][j] * scale, s1 = sacc[1][j] * scale;
      float s2 = sacc[2][j] * scale, s3 = sacc[3][j] * scale;
      float mx = fmaxf(fmaxf(s0, s1), fmaxf(s2, s3));
      mx = fmaxf(mx, __shfl_xor(mx, 1));
      mx = fmaxf(mx, __shfl_xor(mx, 2));
      mx = fmaxf(mx, __shfl_xor(mx, 4));
      mx = fmaxf(mx, __shfl_xor(mx, 8));
      float newm = fmaxf(mst[j], mx);
      float fac = __expf(mst[j] - newm);
      mst[j] = newm;
      float p0 = __expf(s0 - newm), p1 = __expf(s1 - newm);
      float p2 = __expf(s2 - newm), p3 = __expf(s3 - newm);
      int prow = wid * 16 + l4 * 4 + j;
      Ps[prow * 72 +      l15] = __float2bfloat16(p0);
      Ps[prow * 72 + 16 + l15] = __float2bfloat16(p1);
      Ps[prow * 72 + 32 + l15] = __float2bfloat16(p2);
      Ps[prow * 72 + 48 + l15] = __float2bfloat16(p3);
      float ps = p0 + p1 + p2 + p3;
      ps += __shfl_xor(ps, 1);
      ps += __shfl_xor(ps, 2);
      ps += __shfl_xor(ps, 4);
      ps += __shfl_xor(ps, 8);
      lst[j] = lst[j] * fac + ps;
#pragma unroll
      for (int n5 = 0; n5 < 5; n5++) oacc[n5][j] *= fac;
    }

    // ---- PV ----
#pragma unroll
    for (int kf = 0; kf < 2; kf++) {
      short8 ap = *(const short8*)&Ps[(wid * 16 + l15) * 72 + (kf * 4 + l4) * 8];
#pragma unroll
      for (int n5 = 0; n5 < 5; n5++) {
        int hd = n5 * 16 + l15;
        int cc = (kf * 4 + l4) ^ (hd & 7);
        short8 bv = *(const short8*)&Vts[cur][hd * 64 + cc * 8];
        oacc[n5] = __builtin_amdgcn_mfma_f32_16x16x32_bf16(ap, bv, oacc[n5], 0, 0, 0);
      }
    }
    __syncthreads();
    cur ^= 1;
  }

#pragma unroll
  for (int n5 = 0; n5 < 5; n5++)
#pragma unroll
    for (int j = 0; j < 4; j++) {
      int row = qb + wid * 16 + l4 * 4 + j;
      int col = hh * HD + n5 * 16 + l15;
      o[(size_t)row * D + col] = __float2bfloat16(oacc[n5][j] / lst[j]);
    }
}

extern "C" void kernel_launch(void* const* d_in, const int* in_sizes, int n_in,
                              void* d_out, int out_size, void* d_ws, size_t ws_size,
                              hipStream_t stream) {
  const float* hidden = (const float*)d_in[0];
  const float* cosp   = (const float*)d_in[1];
  const float* sinp   = (const float*)d_in[2];
  const float* qkv_w  = (const float*)d_in[3];
  const float* qkv_b  = (const float*)d_in[4];
  const float* proj_w = (const float*)d_in[5];
  const float* proj_b = (const float*)d_in[6];
  const float* ln1_g  = (const float*)d_in[7];
  const float* ln1_b  = (const float*)d_in[8];
  const float* ln2_g  = (const float*)d_in[9];
  const float* ln2_b  = (const float*)d_in[10];
  const float* fc1_w  = (const float*)d_in[11];
  const float* fc1_b  = (const float*)d_in[12];
  const float* fc2_w  = (const float*)d_in[13];
  const float* fc2_b  = (const float*)d_in[14];
  float* x = (float*)d_out;

  char* w = (char*)d_ws;
  auto alloc = [&](size_t bytes) { void* p = (void*)w; w += bytes; return p; };
  bf16* wqkvT  = (bf16*)alloc((size_t)3 * D * D * 2);
  bf16* wprojT = (bf16*)alloc((size_t)D * D * 2);
  bf16* wfc1T  = (bf16*)alloc((size_t)IM * D * 2);
  bf16* wfc2T  = (bf16*)alloc((size_t)D * IM * 2);
  bf16* hbuf   = (bf16*)alloc((size_t)S * D * 2);
  bf16* qkvb   = (bf16*)alloc((size_t)3 * H * S * HD * 2);   // } contiguous:
  bf16* vtbuf  = (bf16*)alloc((size_t)H * HD * S * 2);       // } FC2 partial alias (21.0 MB)
  bf16* obuf   = (bf16*)alloc((size_t)S * D * 2);
  bf16* midb   = (bf16*)alloc((size_t)S * IM * 2);           // proj partial alias (21.0 MB)
  float* Pproj = (float*)midb;   // dead during proj gemm+reduce
  float* Pfc2  = (float*)qkvb;   // qkvb+vtbuf dead after flash; 2*2048*1280*4 == their size
  (void)ws_size; (void)in_sizes; (void)n_in; (void)out_size;

  hipMemcpyAsync(x, hidden, (size_t)S * D * sizeof(float), hipMemcpyDeviceToDevice, stream);

  for (int l = 0; l < 2; l++) {
    transpose_w<<<dim3(3 * D / 32, D / 32), 256, 0, stream>>>(qkv_w + (size_t)l * D * 3 * D, wqkvT, D, 3 * D);
    transpose_w<<<dim3(D / 32, D / 32), 256, 0, stream>>>(proj_w + (size_t)l * D * D, wprojT, D, D);
    transpose_w<<<dim3(IM / 32, D / 32), 256, 0, stream>>>(fc1_w + (size_t)l * D * IM, wfc1T, D, IM);
    transpose_w<<<dim3(D / 32, IM / 32), 256, 0, stream>>>(fc2_w + (size_t)l * IM * D, wfc2T, IM, D);

    layernorm_k<<<S, 256, 0, stream>>>(x, ln1_g + l * D, ln1_b + l * D, hbuf);
    gemm2<0, 3 * D, D, 1><<<dim3(3 * D / 128, S / 128, 1), 256, 0, stream>>>(
        hbuf, wqkvT, qkv_b + (size_t)l * 3 * D, nullptr, qkvb, nullptr);
    rope_k<<<(2 * H * S * (HD / 2)) / 256, 256, 0, stream>>>(
        qkvb, qkvb + (size_t)H * S * HD, cosp, sinp);
    transpose_v<<<dim3(S / 16, HD / 16, H), 256, 0, stream>>>(qkvb + (size_t)2 * H * S * HD, vtbuf);
    flash_k<<<dim3(S / 64, H), 256, 0, stream>>>(
        qkvb, qkvb + (size_t)H * S * HD, vtbuf, obuf);
    gemm2<3, D, D, 2><<<dim3(D / 128, S / 128, 2), 256, 0, stream>>>(
        obuf, wprojT, nullptr, nullptr, nullptr, Pproj);
    reduce_add<<<(S * D) / 1024, 256, 0, stream>>>(Pproj, proj_b + l * D, x);

    layernorm_k<<<S, 256, 0, stream>>>(x, ln2_g + l * D, ln2_b + l * D, hbuf);
    gemm2<2, IM, D, 1><<<dim3(IM / 128, S / 128, 1), 256, 0, stream>>>(
        hbuf, wfc1T, fc1_b + (size_t)l * IM, nullptr, midb, nullptr);
    gemm2<3, D, IM, 2><<<dim3(D / 128, S / 128, 2), 256, 0, stream>>>(
        midb, wfc2T, nullptr, nullptr, nullptr, Pfc2);
    reduce_add<<<(S * D) / 1024, 256, 0, stream>>>(Pfc2, fc2_b + l * D, x);
  }
}